// Round 1
// baseline (1002.481 us; speedup 1.0000x reference)
//
#include <hip/hip_runtime.h>

#define NCOL 2048
#define BLK  256   // 4 waves; each thread owns 8 row elements (2x float4)

__global__ __launch_bounds__(BLK) void sparsemax_kernel(const float* __restrict__ z,
                                                        float* __restrict__ out) {
    const size_t row = blockIdx.x;
    const float4* __restrict__ zr = (const float4*)(z + row * (size_t)NCOL);
    float4* __restrict__ orow     = (float4*)(out + row * (size_t)NCOL);

    const int tid  = threadIdx.x;
    const int lane = tid & 63;
    const int wave = tid >> 6;

    // Load the whole row into registers: 2048 floats = 512 float4, 256 threads -> 2 each.
    float4 a = zr[tid];
    float4 b = zr[tid + BLK];

    __shared__ float s_s[4];
    __shared__ float s_c[4];

    // ---- initial full-row sum -> tau0 = (S - 1) / n ----
    float s = a.x + a.y + a.z + a.w + b.x + b.y + b.z + b.w;
    #pragma unroll
    for (int off = 32; off > 0; off >>= 1) s += __shfl_down(s, off, 64);
    if (lane == 0) s_s[wave] = s;
    __syncthreads();
    float S = s_s[0] + s_s[1] + s_s[2] + s_s[3];
    __syncthreads();

    float tau = (S - 1.0f) * (1.0f / (float)NCOL);

    // ---- Michelot: shrink active set {z > tau}, recompute tau exactly ----
    // Active set shrinks monotonically; when stable, tau_new == tau bitwise
    // (identical reduction order), so the uniform break is exact.
    for (int it = 0; it < 64; ++it) {
        float ss = 0.0f, cc = 0.0f;
        if (a.x > tau) { ss += a.x; cc += 1.0f; }
        if (a.y > tau) { ss += a.y; cc += 1.0f; }
        if (a.z > tau) { ss += a.z; cc += 1.0f; }
        if (a.w > tau) { ss += a.w; cc += 1.0f; }
        if (b.x > tau) { ss += b.x; cc += 1.0f; }
        if (b.y > tau) { ss += b.y; cc += 1.0f; }
        if (b.z > tau) { ss += b.z; cc += 1.0f; }
        if (b.w > tau) { ss += b.w; cc += 1.0f; }

        #pragma unroll
        for (int off = 32; off > 0; off >>= 1) {
            ss += __shfl_down(ss, off, 64);
            cc += __shfl_down(cc, off, 64);
        }
        if (lane == 0) { s_s[wave] = ss; s_c[wave] = cc; }
        __syncthreads();
        ss = s_s[0] + s_s[1] + s_s[2] + s_s[3];
        cc = s_c[0] + s_c[1] + s_c[2] + s_c[3];
        __syncthreads();

        // cc >= 1 always: tau < row max is an invariant of the iteration.
        float tau_new = (ss - 1.0f) / cc;
        if (tau_new == tau) break;   // uniform across block
        tau = tau_new;
    }

    // ---- epilogue: out = max(z - tau, 0), single coalesced pass ----
    float4 o;
    o.x = fmaxf(a.x - tau, 0.0f);
    o.y = fmaxf(a.y - tau, 0.0f);
    o.z = fmaxf(a.z - tau, 0.0f);
    o.w = fmaxf(a.w - tau, 0.0f);
    orow[tid] = o;
    o.x = fmaxf(b.x - tau, 0.0f);
    o.y = fmaxf(b.y - tau, 0.0f);
    o.z = fmaxf(b.z - tau, 0.0f);
    o.w = fmaxf(b.w - tau, 0.0f);
    orow[tid + BLK] = o;
}

extern "C" void kernel_launch(void* const* d_in, const int* in_sizes, int n_in,
                              void* d_out, int out_size, void* d_ws, size_t ws_size,
                              hipStream_t stream) {
    const float* z = (const float*)d_in[0];
    float* out = (float*)d_out;
    const int rows = in_sizes[0] / NCOL;   // (2*16*2048*2048) / 2048 = 65536
    sparsemax_kernel<<<rows, BLK, 0, stream>>>(z, out);
}

// Round 3
// 853.272 us; speedup vs baseline: 1.1749x; 1.1749x over previous
//
#include <hip/hip_runtime.h>

#define NCOL 2048
#define V4   8      // float4 per lane: 8 * 4 * 64 lanes = 2048 elements/row
#define BLK  256    // 4 independent waves per block, one row per wave

typedef float nfloat4 __attribute__((ext_vector_type(4)));  // native vec for NT store

__global__ __launch_bounds__(BLK) void sparsemax_kernel(const float* __restrict__ z,
                                                        float* __restrict__ out,
                                                        int rows) {
    const int tid  = threadIdx.x;
    const int lane = tid & 63;
    const int wave = tid >> 6;
    const int row  = blockIdx.x * 4 + wave;
    if (row >= rows) return;

    const float4* __restrict__ zr = (const float4*)(z + (size_t)row * NCOL);
    nfloat4* __restrict__ orow    = (nfloat4*)(out + (size_t)row * NCOL);

    // Whole row in registers: 32 floats/lane, read HBM exactly once.
    float4 v[V4];
    #pragma unroll
    for (int i = 0; i < V4; ++i) v[i] = zr[lane + 64 * i];

    // ---- prologue: row max (butterfly, all lanes get identical result) ----
    float m = -1e30f;
    #pragma unroll
    for (int i = 0; i < V4; ++i)
        m = fmaxf(m, fmaxf(fmaxf(v[i].x, v[i].y), fmaxf(v[i].z, v[i].w)));
    #pragma unroll
    for (int off = 1; off < 64; off <<= 1)
        m = fmaxf(m, __shfl_xor(m, off, 64));

    // tau* solves g(tau) = sum(max(z - tau, 0)) = 1. g(max-1) >= 1, so
    // tau0 = max-1 is a valid from-below Newton start with a tiny active set.
    float tau = m - 1.0f;

    for (int it = 0; it < 50; ++it) {
        // g via VALU (sub+max+add); count via ballot -> SALU popcount (free pipe).
        float g0 = 0.0f, g1 = 0.0f;   // 2 accumulators to shorten dep chain
        int k = 0;
        #pragma unroll
        for (int i = 0; i < V4; ++i) {
            const float4 t = v[i];
            g0 += fmaxf(t.x - tau, 0.0f);
            g1 += fmaxf(t.y - tau, 0.0f);
            g0 += fmaxf(t.z - tau, 0.0f);
            g1 += fmaxf(t.w - tau, 0.0f);
            k += __popcll(__ballot(t.x > tau));
            k += __popcll(__ballot(t.y > tau));
            k += __popcll(__ballot(t.z > tau));
            k += __popcll(__ballot(t.w > tau));
        }
        float g = g0 + g1;
        #pragma unroll
        for (int off = 1; off < 64; off <<= 1)
            g += __shfl_xor(g, off, 64);   // butterfly: bitwise-uniform across lanes

        // Newton from below on convex decreasing g: monotone, k >= 1 invariant.
        const float tau_new = tau + (g - 1.0f) / (float)k;
        if (tau_new <= tau) break;         // uniform break (all inputs uniform)
        tau = tau_new;
    }

    // ---- epilogue: out = max(z - tau, 0), nontemporal (never re-read) ----
    #pragma unroll
    for (int i = 0; i < V4; ++i) {
        const float4 t = v[i];
        nfloat4 o;
        o.x = fmaxf(t.x - tau, 0.0f);
        o.y = fmaxf(t.y - tau, 0.0f);
        o.z = fmaxf(t.z - tau, 0.0f);
        o.w = fmaxf(t.w - tau, 0.0f);
        __builtin_nontemporal_store(o, &orow[lane + 64 * i]);
    }
}

extern "C" void kernel_launch(void* const* d_in, const int* in_sizes, int n_in,
                              void* d_out, int out_size, void* d_ws, size_t ws_size,
                              hipStream_t stream) {
    const float* z = (const float*)d_in[0];
    float* out = (float*)d_out;
    const int rows = in_sizes[0] / NCOL;          // 65536
    const int grid = (rows + 3) / 4;              // 4 rows (waves) per block
    sparsemax_kernel<<<grid, BLK, 0, stream>>>(z, out, rows);
}